// Round 4
// baseline (595.132 us; speedup 1.0000x reference)
//
#include <hip/hip_runtime.h>
#include <hip/hip_bf16.h>

// Problem constants
#define S_LEN 4096
#define DMODEL 2048
#define NH 16
#define NKV 4
#define HD 128
#define QKV_N 3072   // merged QKV projection width: 2048 Q | 512 K | 512 V

typedef __bf16 bf16x8 __attribute__((ext_vector_type(8)));
typedef float f32x4 __attribute__((ext_vector_type(4)));
typedef unsigned short u16x8 __attribute__((ext_vector_type(8)));
typedef unsigned short u16x4 __attribute__((ext_vector_type(4)));
typedef unsigned long long u64x2 __attribute__((ext_vector_type(2)));

__device__ __forceinline__ unsigned short f2bf(float f) {
    unsigned int u = __builtin_bit_cast(unsigned int, f);
    u += 0x7fffu + ((u >> 16) & 1u);   // round-to-nearest-even
    return (unsigned short)(u >> 16);
}
__device__ __forceinline__ float bf2f(unsigned short h) {
    unsigned int u = ((unsigned int)h) << 16;
    return __builtin_bit_cast(float, u);
}

// Single-instruction packed f32x2 -> bf16x2 (RTNE).
__device__ __forceinline__ unsigned int cvt_pk_bf16(float lo, float hi) {
    unsigned int r;
    asm("v_cvt_pk_bf16_f32 %0, %1, %2" : "=v"(r) : "v"(lo), "v"(hi));
    return r;
}

// Raw v_exp_f32 (2^x); skips ocml denorm fixup.
__device__ __forceinline__ float fast_exp2(float x) {
    float r;
    asm("v_exp_f32 %0, %1" : "=v"(r) : "v"(x));
    return r;
}

__device__ __forceinline__ f32x4 mfma16(bf16x8 a, bf16x8 b, f32x4 c) {
    return __builtin_amdgcn_mfma_f32_16x16x32_bf16(a, b, c, 0, 0, 0);
}

// Async global->LDS DMA, 16B per lane. LDS dest = wave-uniform base + lane*16.
__device__ __forceinline__ void async16(unsigned short* lds, const unsigned short* g) {
    __builtin_amdgcn_global_load_lds((__attribute__((address_space(1))) void*)g,
                                     (__attribute__((address_space(3))) void*)lds,
                                     16, 0, 0);
}

// ---------------------------------------------------------------------------
// fp32 -> bf16 elementwise convert (4 elems/thread, float4 loads)
// ---------------------------------------------------------------------------
__global__ __launch_bounds__(256) void conv_f32_bf16(
    const float* __restrict__ in, unsigned short* __restrict__ out, int n4) {
    int i = blockIdx.x * 256 + threadIdx.x;
    if (i >= n4) return;
    float4 v = *(const float4*)&in[(size_t)i * 4];
    u16x4 o;
    o[0] = f2bf(v.x); o[1] = f2bf(v.y); o[2] = f2bf(v.z); o[3] = f2bf(v.w);
    *(u16x4*)&out[(size_t)i * 4] = o;
}

// ---------------------------------------------------------------------------
// Tiled transpose fp32 in[R][C] -> bf16 out[C][R]. R, C multiples of 32.
// ---------------------------------------------------------------------------
__global__ __launch_bounds__(1024) void transpose_f32_bf16(
    const float* __restrict__ in, unsigned short* __restrict__ out,
    int R, int C) {
    __shared__ float tile[32][33];
    int x = blockIdx.x * 32 + threadIdx.x;
    int y = blockIdx.y * 32 + threadIdx.y;
    tile[threadIdx.y][threadIdx.x] = in[(size_t)y * C + x];
    __syncthreads();
    int ox = blockIdx.y * 32 + threadIdx.x;
    int oy = blockIdx.x * 32 + threadIdx.y;
    out[(size_t)oy * R + ox] = f2bf(tile[threadIdx.x][threadIdx.y]);
}

// ---------------------------------------------------------------------------
// Tiled bf16 transpose with input row stride: in[y*ldin + x] (y<R rows, x<C
// cols) -> out[C][R] contiguous.
// ---------------------------------------------------------------------------
__global__ __launch_bounds__(1024) void transpose_bf16(
    const unsigned short* __restrict__ in, unsigned short* __restrict__ out,
    int R, int C, int ldin) {
    __shared__ unsigned short tile[32][33];
    int x = blockIdx.x * 32 + threadIdx.x;
    int y = blockIdx.y * 32 + threadIdx.y;
    tile[threadIdx.y][threadIdx.x] = in[(size_t)y * ldin + x];
    __syncthreads();
    int ox = blockIdx.y * 32 + threadIdx.x;
    int oy = blockIdx.x * 32 + threadIdx.y;
    out[(size_t)oy * R + ox] = tile[threadIdx.x][threadIdx.y];
}

// ---------------------------------------------------------------------------
// C[M,N] = A[M,K] * B[K,N], B given transposed (Bt[N][K]). bf16 in, fp32
// accumulate, OutT out. 128x128 tile, BK=32, 4 waves of 64x64.
// ---------------------------------------------------------------------------
template <typename OutT>
__global__ __launch_bounds__(256) void gemm_bt(
    const unsigned short* __restrict__ A, const unsigned short* __restrict__ Bt,
    OutT* __restrict__ C, int N, int K) {
    __shared__ __align__(16) unsigned short As[2][128 * 32];  // 8 KB per buf
    __shared__ __align__(16) unsigned short Bs[2][128 * 32];
    const int tid = threadIdx.x;
    const int wave = tid >> 6, lane = tid & 63, quad = lane >> 4, l16 = lane & 15;
    const int m0 = blockIdx.x * 128, n0 = blockIdx.y * 128;
    const int waveM = (wave & 1) * 64, waveN = (wave >> 1) * 64;
    f32x4 acc[4][4] = {};

    auto stage = [&](int k0, int b) {
#pragma unroll
        for (int u = 0; u < 2; u++) {
            const int seg = wave * 2 + u;
            const int idx = seg * 64 + lane;
            const int r = idx >> 2, c = idx & 3;  // granule (r, c): 4x16B per row
            async16(&As[b][seg * 512], &A[(size_t)(m0 + r) * K + k0 + c * 8]);
            async16(&Bs[b][seg * 512], &Bt[(size_t)(n0 + r) * K + k0 + c * 8]);
        }
    };

    const int niter = K / 32;
    stage(0, 0);
    __syncthreads();  // drains vmcnt -> buf0 ready
    for (int it = 0; it < niter; it++) {
        const int b = it & 1;
        if (it + 1 < niter) stage((it + 1) * 32, b ^ 1);
        bf16x8 af[4], bfv[4];
#pragma unroll
        for (int i = 0; i < 4; i++)
            af[i] = *(const bf16x8*)&As[b][(waveM + i * 16 + l16) * 32 + quad * 8];
#pragma unroll
        for (int j = 0; j < 4; j++)
            bfv[j] = *(const bf16x8*)&Bs[b][(waveN + j * 16 + l16) * 32 + quad * 8];
#pragma unroll
        for (int i = 0; i < 4; i++)
#pragma unroll
            for (int j = 0; j < 4; j++)
                acc[i][j] = mfma16(af[i], bfv[j], acc[i][j]);
        __syncthreads();  // drains prefetch (issued ~compute-phase ago) + sync
    }
    // C/D layout: col = lane&15, row = quad*4 + reg (verified m89/m91)
#pragma unroll
    for (int i = 0; i < 4; i++)
#pragma unroll
        for (int j = 0; j < 4; j++)
#pragma unroll
            for (int r = 0; r < 4; r++) {
                int row = m0 + waveM + i * 16 + quad * 4 + r;
                int col = n0 + waveN + j * 16 + l16;
                if constexpr (sizeof(OutT) == 2)
                    C[(size_t)row * N + col] = f2bf(acc[i][j][r]);
                else
                    C[(size_t)row * N + col] = acc[i][j][r];
            }
}

// ---------------------------------------------------------------------------
// RoPE in-place on bf16 X[S][...], row stride `stride` elements; head count
// 2^log2nh at cols h*128. cos/sin fp32 [S][128].
// ---------------------------------------------------------------------------
__global__ __launch_bounds__(256) void rope_kernel(
    unsigned short* __restrict__ X, const float* __restrict__ cb,
    const float* __restrict__ sb, int log2nh, int stride) {
    int idx = blockIdx.x * 256 + threadIdx.x;
    int d = idx & 63;
    int h = (idx >> 6) & ((1 << log2nh) - 1);
    int s = idx >> (6 + log2nh);
    size_t base = (size_t)s * stride + h * HD + d;
    float a = bf2f(X[base]);
    float b = bf2f(X[base + 64]);
    float c0 = cb[s * HD + d];
    float s0 = sb[s * HD + d];
    float c1 = cb[s * HD + d + 64];
    float s1 = sb[s * HD + d + 64];
    X[base]      = f2bf(a * c0 - b * s0);
    X[base + 64] = f2bf(b * c1 + a * s1);
}

// ---------------------------------------------------------------------------
// Flash attention, causal, GQA 16Q/4KV, hd=128.
// LDS-BANDWIDTH-OPTIMIZED structure: q-block = 128 rows, each wave owns
// 32 q-rows (2 x 16-row tiles), k-chunk = 32. Each wave reads the K tile
// (8 KB) and V tile (8 KB) ONCE per chunk and uses them for BOTH q-tiles
// -> ~17.6 B of LDS traffic per k*q unit (vs 32 B for the 1-q-tile/wave
// variant). LDS = 16K (K dbuf) + 16K (V dbuf) + 8K (Ps) = 40 KB -> 2
// blocks/CU (schedulable LDS pool measured ~80 KB: 72->1, 36->2, 32->2).
// Double-buffered global_load_lds staging, one __syncthreads per chunk,
// prefetch issued a full compute-phase before the drain. P goes through a
// wave-private LDS round-trip (bpermute variant measured WORSE: 4.2M bank
// conflicts). Balanced per-CU pairing {31-g, g} (ids i, i+256 share a CU).
// ---------------------------------------------------------------------------
__global__ __launch_bounds__(256, 4) void attn_kernel(
    const unsigned short* __restrict__ Q, const unsigned short* __restrict__ Kv,
    const unsigned short* __restrict__ Vt, unsigned short* __restrict__ O) {
    __shared__ __align__(16) unsigned short Kt[2][32 * 128];   // 8 KB per buf
    __shared__ __align__(16) unsigned short Vs[2][128 * 32];   // 8 KB per buf
    __shared__ __align__(16) unsigned long long Ps[4 * 4 * 64]; // 8 KB
    const int tid = threadIdx.x;
    const int wave = tid >> 6, lane = tid & 63, quad = lane >> 4, l16 = lane & 15;
    const int id = blockIdx.x;
    const int h = id & 15;
    const int qb = (id < 256) ? (31 - (id >> 4)) : ((id - 256) >> 4);
    const int kvh = h >> 2;
    const int rowbase = qb * 128 + wave * 32;
    unsigned long long* Pw = &Ps[wave * 4 * 64];
    const float cexp = 0.08838834764831845f * 1.44269504088896f;  // scale*log2(e)

    // stage chunk c (32 k-rows): K 8KB + V 8KB, 2 segs/wave each.
    auto stage = [&](int c, int b) {
        const int kb = c * 32;
#pragma unroll
        for (int u = 0; u < 2; u++) {
            const int seg = wave * 2 + u;
            const int idx = seg * 64 + lane;
            {   // K tile [32 k][128 d], 16 granules/row, swizzle cs ^ (r&15)
                const int r = idx >> 4, cs = idx & 15, cl = cs ^ (r & 15);
                async16(&Kt[b][seg * 512],
                        &Kv[(size_t)(kb + r) * QKV_N + kvh * HD + cl * 8]);
            }
            {   // V tile [128 d][32 k], 4 granules/row, swizzle cs ^ ((r>>1)&3)
                const int r = idx >> 2, cs = idx & 3, cl = cs ^ ((r >> 1) & 3);
                async16(&Vs[b][seg * 512],
                        &Vt[(size_t)(kvh * HD + r) * S_LEN + kb + cl * 8]);
            }
        }
    };

    // Q fragments (2 q-tiles x 16 rows per wave, reused across all chunks).
    bf16x8 qf[2][4];
#pragma unroll
    for (int i = 0; i < 2; i++)
#pragma unroll
        for (int dd = 0; dd < 4; dd++)
            qf[i][dd] = *(const bf16x8*)&Q[(size_t)(rowbase + i * 16 + l16) * QKV_N +
                                           h * HD + dd * 32 + quad * 8];

    f32x4 oacc[2][8] = {};
    float lrow[2] = {0.0f, 0.0f};
    const int qa0 = rowbase + l16;
    const int qa1 = rowbase + 16 + l16;
    const int nch = 4 * qb + 4;

    stage(0, 0);
    __syncthreads();
    for (int c = 0; c < nch; c++) {
        const int b = c & 1;
        if (c + 1 < nch) stage(c + 1, b ^ 1);
        const int kb = c * 32;
        if (kb <= rowbase + 31) {  // per-wave skip of fully-masked chunks
            const bool diag = (kb + 31 > rowbase);
            // ---- S^T tiles jl = 0,1 (m = k-pos, n = q), both q-tiles ----
            f32x4 sacc[2][2] = {};
            __builtin_amdgcn_s_setprio(1);
#pragma unroll
            for (int dd = 0; dd < 4; dd++) {
                const int csw = (dd * 4 + quad) ^ l16;
                bf16x8 kf0 = *(const bf16x8*)&Kt[b][((0 * 16 + l16) * 16 + csw) * 8];
                bf16x8 kf1 = *(const bf16x8*)&Kt[b][((1 * 16 + l16) * 16 + csw) * 8];
                sacc[0][0] = mfma16(kf0, qf[0][dd], sacc[0][0]);
                sacc[0][1] = mfma16(kf1, qf[0][dd], sacc[0][1]);
                sacc[1][0] = mfma16(kf0, qf[1][dd], sacc[1][0]);
                sacc[1][1] = mfma16(kf1, qf[1][dd], sacc[1][1]);
            }
            __builtin_amdgcn_s_setprio(0);
            // ---- exp, mask, l-partials, pack 4 bf16 -> one 8B LDS write ----
#pragma unroll
            for (int i = 0; i < 2; i++) {
                const int qa = i ? qa1 : qa0;
#pragma unroll
                for (int jl = 0; jl < 2; jl++) {
                    const int kg = kb + 16 * jl + 4 * quad;
                    float p0 = fast_exp2(sacc[i][jl][0] * cexp);
                    float p1 = fast_exp2(sacc[i][jl][1] * cexp);
                    float p2 = fast_exp2(sacc[i][jl][2] * cexp);
                    float p3 = fast_exp2(sacc[i][jl][3] * cexp);
                    if (diag) {
                        if (kg + 0 > qa) p0 = 0.0f;
                        if (kg + 1 > qa) p1 = 0.0f;
                        if (kg + 2 > qa) p2 = 0.0f;
                        if (kg + 3 > qa) p3 = 0.0f;
                    }
                    lrow[i] += (p0 + p1) + (p2 + p3);
                    unsigned int lo = cvt_pk_bf16(p0, p1);
                    unsigned int hi = cvt_pk_bf16(p2, p3);
                    Pw[(i * 2 + jl) * 64 + lane] =
                        (unsigned long long)lo | ((unsigned long long)hi << 32);
                }
            }
            // ---- P A-fragments: two 8B wave-private LDS reads per i ----
            bf16x8 pf[2];
#pragma unroll
            for (int i = 0; i < 2; i++) {
                const unsigned long long* src =
                    &Pw[(i * 2 + (quad >> 1)) * 64 + l16 + 32 * (quad & 1)];
                u64x2 t;
                t[0] = src[0];
                t[1] = src[16];
                pf[i] = __builtin_bit_cast(bf16x8, t);
            }
            // ---- O += P V: V tile read ONCE, used for both q-tiles ----
            const int vsw0 = (quad ^ ((l16 >> 1) & 3)) * 8;
            __builtin_amdgcn_s_setprio(1);
#pragma unroll
            for (int jd = 0; jd < 8; jd++) {
                bf16x8 vf = *(const bf16x8*)&Vs[b][(jd * 16 + l16) * 32 + vsw0];
                oacc[0][jd] = mfma16(pf[0], vf, oacc[0][jd]);
                oacc[1][jd] = mfma16(pf[1], vf, oacc[1][jd]);
            }
            __builtin_amdgcn_s_setprio(0);
        }
        __syncthreads();  // drains prefetch (issued compute-phase ago) + sync
    }
    // ---- epilogue: row sums, O /= l, write [S][NH*HD] ----
    float lsum[2];
#pragma unroll
    for (int i = 0; i < 2; i++) {
        float l = lrow[i];
        l += __shfl_xor(l, 16, 64);
        l += __shfl_xor(l, 32, 64);
        lsum[i] = l;
    }
#pragma unroll
    for (int i = 0; i < 2; i++)
#pragma unroll
        for (int r = 0; r < 4; r++) {
            float lq = __shfl(lsum[i], quad * 4 + r, 64);
            float inv = 1.0f / lq;
            int row = rowbase + i * 16 + quad * 4 + r;
#pragma unroll
            for (int jd = 0; jd < 8; jd++)
                O[(size_t)row * DMODEL + h * HD + jd * 16 + l16] = f2bf(oacc[i][jd][r] * inv);
        }
}

// ---------------------------------------------------------------------------
extern "C" void kernel_launch(void* const* d_in, const int* in_sizes, int n_in,
                              void* d_out, int out_size, void* d_ws, size_t ws_size,
                              hipStream_t stream) {
    const float* X  = (const float*)d_in[0];  // hidden [4096][2048]
    const float* cb = (const float*)d_in[1];  // cos [4096][128]
    const float* sb = (const float*)d_in[2];  // sin [4096][128]
    const float* Wq = (const float*)d_in[3];  // [2048][2048]
    const float* Wk = (const float*)d_in[4];  // [2048][512]
    const float* Wv = (const float*)d_in[5];  // [2048][512]
    const float* Wo = (const float*)d_in[6];  // [2048][2048]
    float* out = (float*)d_out;               // [4096][2048] fp32

    char* ws = (char*)d_ws;
    size_t off = 0;
    auto alloc = [&](size_t bytes) { char* p = ws + off; off += (bytes + 255) & ~(size_t)255; return p; };
    unsigned short* Xb    = (unsigned short*)alloc((size_t)S_LEN * DMODEL * 2);
    unsigned short* QKVb  = (unsigned short*)alloc((size_t)S_LEN * QKV_N * 2);   // [4096][3072]
    unsigned short* Vtb   = (unsigned short*)alloc((size_t)S_LEN * NKV * HD * 2); // [512][4096]
    unsigned short* Ob    = (unsigned short*)alloc((size_t)S_LEN * DMODEL * 2);
    unsigned short* WqkvT = (unsigned short*)alloc((size_t)QKV_N * DMODEL * 2);  // [3072][2048]
    unsigned short* WoT   = (unsigned short*)alloc((size_t)DMODEL * DMODEL * 2);

    // hidden fp32 -> bf16
    conv_f32_bf16<<<(S_LEN * DMODEL / 4 + 255) / 256, 256, 0, stream>>>(X, Xb, S_LEN * DMODEL / 4);

    dim3 tb(32, 32);
    // Weight transposes (fp32 -> bf16), stacked [Wq^T; Wk^T; Wv^T] = [3072][2048].
    transpose_f32_bf16<<<dim3(DMODEL / 32, DMODEL / 32), tb, 0, stream>>>(Wq, WqkvT, DMODEL, DMODEL);
    transpose_f32_bf16<<<dim3((NKV * HD) / 32, DMODEL / 32), tb, 0, stream>>>(Wk, WqkvT + (size_t)DMODEL * DMODEL, DMODEL, NKV * HD);
    transpose_f32_bf16<<<dim3((NKV * HD) / 32, DMODEL / 32), tb, 0, stream>>>(Wv, WqkvT + (size_t)(DMODEL + NKV * HD) * DMODEL, DMODEL, NKV * HD);
    transpose_f32_bf16<<<dim3(DMODEL / 32, DMODEL / 32), tb, 0, stream>>>(Wo, WoT, DMODEL, DMODEL);

    // Merged QKV projection: N = 3072 (cols 0..2047 Q | 2048..2559 K | 2560..3071 V)
    gemm_bt<unsigned short><<<dim3(S_LEN / 128, QKV_N / 128), 256, 0, stream>>>(Xb, WqkvT, QKVb, QKV_N, DMODEL);

    // RoPE in place: Q (stride 3072, 16 heads), K (stride 3072, 4 heads)
    rope_kernel<<<(S_LEN * NH * 64) / 256, 256, 0, stream>>>(QKVb, cb, sb, 4, QKV_N);
    rope_kernel<<<(S_LEN * NKV * 64) / 256, 256, 0, stream>>>(QKVb + DMODEL, cb, sb, 2, QKV_N);

    // V columns of QKVb -> Vt [512][4096]
    transpose_bf16<<<dim3((NKV * HD) / 32, S_LEN / 32), tb, 0, stream>>>(
        QKVb + DMODEL + NKV * HD, Vtb, S_LEN, NKV * HD, QKV_N);

    // Flash attention: 512 blocks (q-block=128), 40 KB LDS -> 2 blocks/CU
    attn_kernel<<<512, 256, 0, stream>>>(QKVb, QKVb + DMODEL, Vtb, Ob);

    // Output projection (fp32 out)
    gemm_bt<float><<<dim3(S_LEN / 128, DMODEL / 128), 256, 0, stream>>>(Ob, WoT, out, DMODEL, DMODEL);
}

// Round 5
// 411.638 us; speedup vs baseline: 1.4458x; 1.4458x over previous
//
#include <hip/hip_runtime.h>
#include <hip/hip_bf16.h>

// Problem constants
#define S_LEN 4096
#define DMODEL 2048
#define NH 16
#define NKV 4
#define HD 128
#define QKV_N 3072   // merged QKV projection width: 2048 Q | 512 K | 512 V

typedef __bf16 bf16x8 __attribute__((ext_vector_type(8)));
typedef float f32x4 __attribute__((ext_vector_type(4)));
typedef unsigned short u16x8 __attribute__((ext_vector_type(8)));
typedef unsigned short u16x4 __attribute__((ext_vector_type(4)));
typedef unsigned long long u64x2 __attribute__((ext_vector_type(2)));

__device__ __forceinline__ unsigned short f2bf(float f) {
    unsigned int u = __builtin_bit_cast(unsigned int, f);
    u += 0x7fffu + ((u >> 16) & 1u);   // round-to-nearest-even
    return (unsigned short)(u >> 16);
}
__device__ __forceinline__ float bf2f(unsigned short h) {
    unsigned int u = ((unsigned int)h) << 16;
    return __builtin_bit_cast(float, u);
}

// Single-instruction packed f32x2 -> bf16x2 (RTNE).
__device__ __forceinline__ unsigned int cvt_pk_bf16(float lo, float hi) {
    unsigned int r;
    asm("v_cvt_pk_bf16_f32 %0, %1, %2" : "=v"(r) : "v"(lo), "v"(hi));
    return r;
}

// Raw v_exp_f32 (2^x); skips ocml denorm fixup.
__device__ __forceinline__ float fast_exp2(float x) {
    float r;
    asm("v_exp_f32 %0, %1" : "=v"(r) : "v"(x));
    return r;
}

__device__ __forceinline__ f32x4 mfma16(bf16x8 a, bf16x8 b, f32x4 c) {
    return __builtin_amdgcn_mfma_f32_16x16x32_bf16(a, b, c, 0, 0, 0);
}

// Async global->LDS DMA, 16B per lane. LDS dest = wave-uniform base + lane*16.
__device__ __forceinline__ void async16(unsigned short* lds, const unsigned short* g) {
    __builtin_amdgcn_global_load_lds((__attribute__((address_space(1))) void*)g,
                                     (__attribute__((address_space(3))) void*)lds,
                                     16, 0, 0);
}

// ---------------------------------------------------------------------------
// fp32 -> bf16 elementwise convert (4 elems/thread, float4 loads)
// ---------------------------------------------------------------------------
__global__ __launch_bounds__(256) void conv_f32_bf16(
    const float* __restrict__ in, unsigned short* __restrict__ out, int n4) {
    int i = blockIdx.x * 256 + threadIdx.x;
    if (i >= n4) return;
    float4 v = *(const float4*)&in[(size_t)i * 4];
    u16x4 o;
    o[0] = f2bf(v.x); o[1] = f2bf(v.y); o[2] = f2bf(v.z); o[3] = f2bf(v.w);
    *(u16x4*)&out[(size_t)i * 4] = o;
}

// ---------------------------------------------------------------------------
// Tiled transpose fp32 in[R][C] -> bf16 out[C][R]. R, C multiples of 32.
// ---------------------------------------------------------------------------
__global__ __launch_bounds__(1024) void transpose_f32_bf16(
    const float* __restrict__ in, unsigned short* __restrict__ out,
    int R, int C) {
    __shared__ float tile[32][33];
    int x = blockIdx.x * 32 + threadIdx.x;
    int y = blockIdx.y * 32 + threadIdx.y;
    tile[threadIdx.y][threadIdx.x] = in[(size_t)y * C + x];
    __syncthreads();
    int ox = blockIdx.y * 32 + threadIdx.x;
    int oy = blockIdx.x * 32 + threadIdx.y;
    out[(size_t)oy * R + ox] = f2bf(tile[threadIdx.x][threadIdx.y]);
}

// ---------------------------------------------------------------------------
// Tiled bf16 transpose with input row stride: in[y*ldin + x] (y<R rows, x<C
// cols) -> out[C][R] contiguous.
// ---------------------------------------------------------------------------
__global__ __launch_bounds__(1024) void transpose_bf16(
    const unsigned short* __restrict__ in, unsigned short* __restrict__ out,
    int R, int C, int ldin) {
    __shared__ unsigned short tile[32][33];
    int x = blockIdx.x * 32 + threadIdx.x;
    int y = blockIdx.y * 32 + threadIdx.y;
    tile[threadIdx.y][threadIdx.x] = in[(size_t)y * ldin + x];
    __syncthreads();
    int ox = blockIdx.y * 32 + threadIdx.x;
    int oy = blockIdx.x * 32 + threadIdx.y;
    out[(size_t)oy * R + ox] = tile[threadIdx.x][threadIdx.y];
}

// ---------------------------------------------------------------------------
// C[M,N] = A[M,K] * B[K,N], B given transposed (Bt[N][K]). bf16 in, fp32
// accumulate, OutT out. 128x128 tile, BK=32, 4 waves of 64x64.
// ---------------------------------------------------------------------------
template <typename OutT>
__global__ __launch_bounds__(256) void gemm_bt(
    const unsigned short* __restrict__ A, const unsigned short* __restrict__ Bt,
    OutT* __restrict__ C, int N, int K) {
    __shared__ __align__(16) unsigned short As[2][128 * 32];  // 8 KB per buf
    __shared__ __align__(16) unsigned short Bs[2][128 * 32];
    const int tid = threadIdx.x;
    const int wave = tid >> 6, lane = tid & 63, quad = lane >> 4, l16 = lane & 15;
    const int m0 = blockIdx.x * 128, n0 = blockIdx.y * 128;
    const int waveM = (wave & 1) * 64, waveN = (wave >> 1) * 64;
    f32x4 acc[4][4] = {};

    auto stage = [&](int k0, int b) {
#pragma unroll
        for (int u = 0; u < 2; u++) {
            const int seg = wave * 2 + u;
            const int idx = seg * 64 + lane;
            const int r = idx >> 2, c = idx & 3;  // granule (r, c): 4x16B per row
            async16(&As[b][seg * 512], &A[(size_t)(m0 + r) * K + k0 + c * 8]);
            async16(&Bs[b][seg * 512], &Bt[(size_t)(n0 + r) * K + k0 + c * 8]);
        }
    };

    const int niter = K / 32;
    stage(0, 0);
    __syncthreads();  // drains vmcnt -> buf0 ready
    for (int it = 0; it < niter; it++) {
        const int b = it & 1;
        if (it + 1 < niter) stage((it + 1) * 32, b ^ 1);
        bf16x8 af[4], bfv[4];
#pragma unroll
        for (int i = 0; i < 4; i++)
            af[i] = *(const bf16x8*)&As[b][(waveM + i * 16 + l16) * 32 + quad * 8];
#pragma unroll
        for (int j = 0; j < 4; j++)
            bfv[j] = *(const bf16x8*)&Bs[b][(waveN + j * 16 + l16) * 32 + quad * 8];
#pragma unroll
        for (int i = 0; i < 4; i++)
#pragma unroll
            for (int j = 0; j < 4; j++)
                acc[i][j] = mfma16(af[i], bfv[j], acc[i][j]);
        __syncthreads();  // drains prefetch (issued ~compute-phase ago) + sync
    }
    // C/D layout: col = lane&15, row = quad*4 + reg (verified m89/m91)
#pragma unroll
    for (int i = 0; i < 4; i++)
#pragma unroll
        for (int j = 0; j < 4; j++)
#pragma unroll
            for (int r = 0; r < 4; r++) {
                int row = m0 + waveM + i * 16 + quad * 4 + r;
                int col = n0 + waveN + j * 16 + l16;
                if constexpr (sizeof(OutT) == 2)
                    C[(size_t)row * N + col] = f2bf(acc[i][j][r]);
                else
                    C[(size_t)row * N + col] = acc[i][j][r];
            }
}

// ---------------------------------------------------------------------------
// RoPE in-place on bf16 X[S][...], row stride `stride` elements; head count
// 2^log2nh at cols h*128. cos/sin fp32 [S][128].
// ---------------------------------------------------------------------------
__global__ __launch_bounds__(256) void rope_kernel(
    unsigned short* __restrict__ X, const float* __restrict__ cb,
    const float* __restrict__ sb, int log2nh, int stride) {
    int idx = blockIdx.x * 256 + threadIdx.x;
    int d = idx & 63;
    int h = (idx >> 6) & ((1 << log2nh) - 1);
    int s = idx >> (6 + log2nh);
    size_t base = (size_t)s * stride + h * HD + d;
    float a = bf2f(X[base]);
    float b = bf2f(X[base + 64]);
    float c0 = cb[s * HD + d];
    float s0 = sb[s * HD + d];
    float c1 = cb[s * HD + d + 64];
    float s1 = sb[s * HD + d + 64];
    X[base]      = f2bf(a * c0 - b * s0);
    X[base + 64] = f2bf(b * c1 + a * s1);
}

// ---------------------------------------------------------------------------
// Flash attention, causal, GQA 16Q/4KV, hd=128.
// LDS-BANDWIDTH structure: q-block = 128 rows, each wave owns 32 q-rows
// (2 x 16-row tiles), k-chunk = 32. Each wave reads the K tile (8 KB) and
// V tile (8 KB) ONCE per chunk, used for BOTH q-tiles -> ~16 B LDS traffic
// per k*q unit (vs 32 B for 1-q-tile/wave). LDS = 40 KB, grid 512.
// __launch_bounds__(256, 2): measured cap table on this toolchain is
// (256,2) -> >=112 VGPR ok; (256,4)/(256,8) -> 64-VGPR cap. R4 used (256,4)
// and the ~124-reg body spilled to scratch (VGPR=64, WRITE_SIZE doubled,
// 2.6x slower). This kernel needs ~112-124 regs -> (256,2) is mandatory.
// Double-buffered global_load_lds staging, one __syncthreads per chunk,
// prefetch issued a full compute-phase before the drain. P via wave-private
// LDS round-trip (bpermute variant measured WORSE: 4.2M bank conflicts).
// Balanced per-CU pairing: blocks i and i+256 share a CU, qb sums = 31.
// ---------------------------------------------------------------------------
__global__ __launch_bounds__(256, 2) void attn_kernel(
    const unsigned short* __restrict__ Q, const unsigned short* __restrict__ Kv,
    const unsigned short* __restrict__ Vt, unsigned short* __restrict__ O) {
    __shared__ __align__(16) unsigned short Kt[2][32 * 128];   // 8 KB per buf
    __shared__ __align__(16) unsigned short Vs[2][128 * 32];   // 8 KB per buf
    __shared__ __align__(16) unsigned long long Ps[4 * 4 * 64]; // 8 KB
    const int tid = threadIdx.x;
    const int wave = tid >> 6, lane = tid & 63, quad = lane >> 4, l16 = lane & 15;
    const int id = blockIdx.x;
    const int h = id & 15;
    const int qb = (id < 256) ? (31 - (id >> 4)) : ((id - 256) >> 4);
    const int kvh = h >> 2;
    const int rowbase = qb * 128 + wave * 32;
    unsigned long long* Pw = &Ps[wave * 4 * 64];
    const float cexp = 0.08838834764831845f * 1.44269504088896f;  // scale*log2(e)

    // stage chunk c (32 k-rows): K 8KB + V 8KB, 2 segs/wave each.
    auto stage = [&](int c, int b) {
        const int kb = c * 32;
#pragma unroll
        for (int u = 0; u < 2; u++) {
            const int seg = wave * 2 + u;
            const int idx = seg * 64 + lane;
            {   // K tile [32 k][128 d], 16 granules/row, swizzle cs ^ (r&15)
                const int r = idx >> 4, cs = idx & 15, cl = cs ^ (r & 15);
                async16(&Kt[b][seg * 512],
                        &Kv[(size_t)(kb + r) * QKV_N + kvh * HD + cl * 8]);
            }
            {   // V tile [128 d][32 k], 4 granules/row, swizzle cs ^ ((r>>1)&3)
                const int r = idx >> 2, cs = idx & 3, cl = cs ^ ((r >> 1) & 3);
                async16(&Vs[b][seg * 512],
                        &Vt[(size_t)(kvh * HD + r) * S_LEN + kb + cl * 8]);
            }
        }
    };

    // Q fragments (2 q-tiles x 16 rows per wave, reused across all chunks).
    bf16x8 qf[2][4];
#pragma unroll
    for (int i = 0; i < 2; i++)
#pragma unroll
        for (int dd = 0; dd < 4; dd++)
            qf[i][dd] = *(const bf16x8*)&Q[(size_t)(rowbase + i * 16 + l16) * QKV_N +
                                           h * HD + dd * 32 + quad * 8];

    f32x4 oacc[2][8] = {};
    float lrow[2] = {0.0f, 0.0f};
    const int qa0 = rowbase + l16;
    const int qa1 = rowbase + 16 + l16;
    const int nch = 4 * qb + 4;

    stage(0, 0);
    __syncthreads();
    for (int c = 0; c < nch; c++) {
        const int b = c & 1;
        if (c + 1 < nch) stage(c + 1, b ^ 1);
        const int kb = c * 32;
        if (kb <= rowbase + 31) {  // per-wave skip of fully-masked chunks
            const bool diag = (kb + 31 > rowbase);
            // ---- S^T tiles jl = 0,1 (m = k-pos, n = q), both q-tiles ----
            f32x4 sacc[2][2] = {};
            __builtin_amdgcn_s_setprio(1);
#pragma unroll
            for (int dd = 0; dd < 4; dd++) {
                const int csw = (dd * 4 + quad) ^ l16;
                bf16x8 kf0 = *(const bf16x8*)&Kt[b][((0 * 16 + l16) * 16 + csw) * 8];
                bf16x8 kf1 = *(const bf16x8*)&Kt[b][((1 * 16 + l16) * 16 + csw) * 8];
                sacc[0][0] = mfma16(kf0, qf[0][dd], sacc[0][0]);
                sacc[0][1] = mfma16(kf1, qf[0][dd], sacc[0][1]);
                sacc[1][0] = mfma16(kf0, qf[1][dd], sacc[1][0]);
                sacc[1][1] = mfma16(kf1, qf[1][dd], sacc[1][1]);
            }
            __builtin_amdgcn_s_setprio(0);
            // ---- exp, mask, l-partials, pack 4 bf16 -> one 8B LDS write ----
#pragma unroll
            for (int i = 0; i < 2; i++) {
                const int qa = i ? qa1 : qa0;
#pragma unroll
                for (int jl = 0; jl < 2; jl++) {
                    const int kg = kb + 16 * jl + 4 * quad;
                    float p0 = fast_exp2(sacc[i][jl][0] * cexp);
                    float p1 = fast_exp2(sacc[i][jl][1] * cexp);
                    float p2 = fast_exp2(sacc[i][jl][2] * cexp);
                    float p3 = fast_exp2(sacc[i][jl][3] * cexp);
                    if (diag) {
                        if (kg + 0 > qa) p0 = 0.0f;
                        if (kg + 1 > qa) p1 = 0.0f;
                        if (kg + 2 > qa) p2 = 0.0f;
                        if (kg + 3 > qa) p3 = 0.0f;
                    }
                    lrow[i] += (p0 + p1) + (p2 + p3);
                    unsigned int lo = cvt_pk_bf16(p0, p1);
                    unsigned int hi = cvt_pk_bf16(p2, p3);
                    Pw[(i * 2 + jl) * 64 + lane] =
                        (unsigned long long)lo | ((unsigned long long)hi << 32);
                }
            }
            // ---- P A-fragments: two 8B wave-private LDS reads per i ----
            bf16x8 pf[2];
#pragma unroll
            for (int i = 0; i < 2; i++) {
                const unsigned long long* src =
                    &Pw[(i * 2 + (quad >> 1)) * 64 + l16 + 32 * (quad & 1)];
                u64x2 t;
                t[0] = src[0];
                t[1] = src[16];
                pf[i] = __builtin_bit_cast(bf16x8, t);
            }
            // ---- O += P V: V tile read ONCE, used for both q-tiles ----
            const int vsw0 = (quad ^ ((l16 >> 1) & 3)) * 8;
            __builtin_amdgcn_s_setprio(1);
#pragma unroll
            for (int jd = 0; jd < 8; jd++) {
                bf16x8 vf = *(const bf16x8*)&Vs[b][(jd * 16 + l16) * 32 + vsw0];
                oacc[0][jd] = mfma16(pf[0], vf, oacc[0][jd]);
                oacc[1][jd] = mfma16(pf[1], vf, oacc[1][jd]);
            }
            __builtin_amdgcn_s_setprio(0);
        }
        __syncthreads();  // drains prefetch (issued compute-phase ago) + sync
    }
    // ---- epilogue: row sums, O /= l, write [S][NH*HD] ----
    float lsum[2];
#pragma unroll
    for (int i = 0; i < 2; i++) {
        float l = lrow[i];
        l += __shfl_xor(l, 16, 64);
        l += __shfl_xor(l, 32, 64);
        lsum[i] = l;
    }
#pragma unroll
    for (int i = 0; i < 2; i++)
#pragma unroll
        for (int r = 0; r < 4; r++) {
            float lq = __shfl(lsum[i], quad * 4 + r, 64);
            float inv = 1.0f / lq;
            int row = rowbase + i * 16 + quad * 4 + r;
#pragma unroll
            for (int jd = 0; jd < 8; jd++)
                O[(size_t)row * DMODEL + h * HD + jd * 16 + l16] = f2bf(oacc[i][jd][r] * inv);
        }
}

// ---------------------------------------------------------------------------
extern "C" void kernel_launch(void* const* d_in, const int* in_sizes, int n_in,
                              void* d_out, int out_size, void* d_ws, size_t ws_size,
                              hipStream_t stream) {
    const float* X  = (const float*)d_in[0];  // hidden [4096][2048]
    const float* cb = (const float*)d_in[1];  // cos [4096][128]
    const float* sb = (const float*)d_in[2];  // sin [4096][128]
    const float* Wq = (const float*)d_in[3];  // [2048][2048]
    const float* Wk = (const float*)d_in[4];  // [2048][512]
    const float* Wv = (const float*)d_in[5];  // [2048][512]
    const float* Wo = (const float*)d_in[6];  // [2048][2048]
    float* out = (float*)d_out;               // [4096][2048] fp32

    char* ws = (char*)d_ws;
    size_t off = 0;
    auto alloc = [&](size_t bytes) { char* p = ws + off; off += (bytes + 255) & ~(size_t)255; return p; };
    unsigned short* Xb    = (unsigned short*)alloc((size_t)S_LEN * DMODEL * 2);
    unsigned short* QKVb  = (unsigned short*)alloc((size_t)S_LEN * QKV_N * 2);   // [4096][3072]
    unsigned short* Vtb   = (unsigned short*)alloc((size_t)S_LEN * NKV * HD * 2); // [512][4096]
    unsigned short* Ob    = (unsigned short*)alloc((size_t)S_LEN * DMODEL * 2);
    unsigned short* WqkvT = (unsigned short*)alloc((size_t)QKV_N * DMODEL * 2);  // [3072][2048]
    unsigned short* WoT   = (unsigned short*)alloc((size_t)DMODEL * DMODEL * 2);

    // hidden fp32 -> bf16
    conv_f32_bf16<<<(S_LEN * DMODEL / 4 + 255) / 256, 256, 0, stream>>>(X, Xb, S_LEN * DMODEL / 4);

    dim3 tb(32, 32);
    // Weight transposes (fp32 -> bf16), stacked [Wq^T; Wk^T; Wv^T] = [3072][2048].
    transpose_f32_bf16<<<dim3(DMODEL / 32, DMODEL / 32), tb, 0, stream>>>(Wq, WqkvT, DMODEL, DMODEL);
    transpose_f32_bf16<<<dim3((NKV * HD) / 32, DMODEL / 32), tb, 0, stream>>>(Wk, WqkvT + (size_t)DMODEL * DMODEL, DMODEL, NKV * HD);
    transpose_f32_bf16<<<dim3((NKV * HD) / 32, DMODEL / 32), tb, 0, stream>>>(Wv, WqkvT + (size_t)(DMODEL + NKV * HD) * DMODEL, DMODEL, NKV * HD);
    transpose_f32_bf16<<<dim3(DMODEL / 32, DMODEL / 32), tb, 0, stream>>>(Wo, WoT, DMODEL, DMODEL);

    // Merged QKV projection: N = 3072 (cols 0..2047 Q | 2048..2559 K | 2560..3071 V)
    gemm_bt<unsigned short><<<dim3(S_LEN / 128, QKV_N / 128), 256, 0, stream>>>(Xb, WqkvT, QKVb, QKV_N, DMODEL);

    // RoPE in place: Q (stride 3072, 16 heads), K (stride 3072, 4 heads)
    rope_kernel<<<(S_LEN * NH * 64) / 256, 256, 0, stream>>>(QKVb, cb, sb, 4, QKV_N);
    rope_kernel<<<(S_LEN * NKV * 64) / 256, 256, 0, stream>>>(QKVb + DMODEL, cb, sb, 2, QKV_N);

    // V columns of QKVb -> Vt [512][4096]
    transpose_bf16<<<dim3((NKV * HD) / 32, S_LEN / 32), tb, 0, stream>>>(
        QKVb + DMODEL + NKV * HD, Vtb, S_LEN, NKV * HD, QKV_N);

    // Flash attention: 512 blocks (q-block=128), 40 KB LDS, (256,2) -> no spill
    attn_kernel<<<512, 256, 0, stream>>>(QKVb, QKVb + DMODEL, Vtb, Ob);

    // Output projection (fp32 out)
    gemm_bt<float><<<dim3(S_LEN / 128, DMODEL / 128), 256, 0, stream>>>(Ob, WoT, out, DMODEL, DMODEL);
}

// Round 6
// 410.586 us; speedup vs baseline: 1.4495x; 1.0026x over previous
//
#include <hip/hip_runtime.h>
#include <hip/hip_bf16.h>

// Problem constants
#define S_LEN 4096
#define DMODEL 2048
#define NH 16
#define NKV 4
#define HD 128
#define QKV_N 3072   // merged QKV projection width: 2048 Q | 512 K | 512 V

typedef __bf16 bf16x8 __attribute__((ext_vector_type(8)));
typedef float f32x4 __attribute__((ext_vector_type(4)));
typedef unsigned short u16x8 __attribute__((ext_vector_type(8)));
typedef unsigned short u16x4 __attribute__((ext_vector_type(4)));
typedef unsigned long long u64x2 __attribute__((ext_vector_type(2)));

__device__ __forceinline__ unsigned short f2bf(float f) {
    unsigned int u = __builtin_bit_cast(unsigned int, f);
    u += 0x7fffu + ((u >> 16) & 1u);   // round-to-nearest-even
    return (unsigned short)(u >> 16);
}
__device__ __forceinline__ float bf2f(unsigned short h) {
    unsigned int u = ((unsigned int)h) << 16;
    return __builtin_bit_cast(float, u);
}

// Single-instruction packed f32x2 -> bf16x2 (RTNE).
__device__ __forceinline__ unsigned int cvt_pk_bf16(float lo, float hi) {
    unsigned int r;
    asm("v_cvt_pk_bf16_f32 %0, %1, %2" : "=v"(r) : "v"(lo), "v"(hi));
    return r;
}

// Raw v_exp_f32 (2^x); skips ocml denorm fixup.
__device__ __forceinline__ float fast_exp2(float x) {
    float r;
    asm("v_exp_f32 %0, %1" : "=v"(r) : "v"(x));
    return r;
}

__device__ __forceinline__ f32x4 mfma16(bf16x8 a, bf16x8 b, f32x4 c) {
    return __builtin_amdgcn_mfma_f32_16x16x32_bf16(a, b, c, 0, 0, 0);
}

// Async global->LDS DMA, 16B per lane. LDS dest = wave-uniform base + lane*16.
__device__ __forceinline__ void async16(unsigned short* lds, const unsigned short* g) {
    __builtin_amdgcn_global_load_lds((__attribute__((address_space(1))) void*)g,
                                     (__attribute__((address_space(3))) void*)lds,
                                     16, 0, 0);
}

// ---------------------------------------------------------------------------
// fp32 -> bf16 elementwise convert (4 elems/thread, float4 loads)
// ---------------------------------------------------------------------------
__global__ __launch_bounds__(256) void conv_f32_bf16(
    const float* __restrict__ in, unsigned short* __restrict__ out, int n4) {
    int i = blockIdx.x * 256 + threadIdx.x;
    if (i >= n4) return;
    float4 v = *(const float4*)&in[(size_t)i * 4];
    u16x4 o;
    o[0] = f2bf(v.x); o[1] = f2bf(v.y); o[2] = f2bf(v.z); o[3] = f2bf(v.w);
    *(u16x4*)&out[(size_t)i * 4] = o;
}

// ---------------------------------------------------------------------------
// Tiled transpose fp32 in[R][C] -> bf16 out[C][R]. R, C multiples of 32.
// ---------------------------------------------------------------------------
__global__ __launch_bounds__(1024) void transpose_f32_bf16(
    const float* __restrict__ in, unsigned short* __restrict__ out,
    int R, int C) {
    __shared__ float tile[32][33];
    int x = blockIdx.x * 32 + threadIdx.x;
    int y = blockIdx.y * 32 + threadIdx.y;
    tile[threadIdx.y][threadIdx.x] = in[(size_t)y * C + x];
    __syncthreads();
    int ox = blockIdx.y * 32 + threadIdx.x;
    int oy = blockIdx.x * 32 + threadIdx.y;
    out[(size_t)oy * R + ox] = f2bf(tile[threadIdx.x][threadIdx.y]);
}

// ---------------------------------------------------------------------------
// Tiled bf16 transpose with input row stride: in[y*ldin + x] (y<R rows, x<C
// cols) -> out[C][R] contiguous.
// ---------------------------------------------------------------------------
__global__ __launch_bounds__(1024) void transpose_bf16(
    const unsigned short* __restrict__ in, unsigned short* __restrict__ out,
    int R, int C, int ldin) {
    __shared__ unsigned short tile[32][33];
    int x = blockIdx.x * 32 + threadIdx.x;
    int y = blockIdx.y * 32 + threadIdx.y;
    tile[threadIdx.y][threadIdx.x] = in[(size_t)y * ldin + x];
    __syncthreads();
    int ox = blockIdx.y * 32 + threadIdx.x;
    int oy = blockIdx.x * 32 + threadIdx.y;
    out[(size_t)oy * R + ox] = tile[threadIdx.x][threadIdx.y];
}

// ---------------------------------------------------------------------------
// C[M,N] = A[M,K] * B[K,N], B given transposed (Bt[N][K]). bf16 in, fp32
// accumulate, OutT out. 128x128 tile, BK=32, 4 waves of 64x64.
// ---------------------------------------------------------------------------
template <typename OutT>
__global__ __launch_bounds__(256) void gemm_bt(
    const unsigned short* __restrict__ A, const unsigned short* __restrict__ Bt,
    OutT* __restrict__ C, int N, int K) {
    __shared__ __align__(16) unsigned short As[2][128 * 32];  // 8 KB per buf
    __shared__ __align__(16) unsigned short Bs[2][128 * 32];
    const int tid = threadIdx.x;
    const int wave = tid >> 6, lane = tid & 63, quad = lane >> 4, l16 = lane & 15;
    const int m0 = blockIdx.x * 128, n0 = blockIdx.y * 128;
    const int waveM = (wave & 1) * 64, waveN = (wave >> 1) * 64;
    f32x4 acc[4][4] = {};

    auto stage = [&](int k0, int b) {
#pragma unroll
        for (int u = 0; u < 2; u++) {
            const int seg = wave * 2 + u;
            const int idx = seg * 64 + lane;
            const int r = idx >> 2, c = idx & 3;  // granule (r, c): 4x16B per row
            async16(&As[b][seg * 512], &A[(size_t)(m0 + r) * K + k0 + c * 8]);
            async16(&Bs[b][seg * 512], &Bt[(size_t)(n0 + r) * K + k0 + c * 8]);
        }
    };

    const int niter = K / 32;
    stage(0, 0);
    __syncthreads();  // drains vmcnt -> buf0 ready
    for (int it = 0; it < niter; it++) {
        const int b = it & 1;
        if (it + 1 < niter) stage((it + 1) * 32, b ^ 1);
        bf16x8 af[4], bfv[4];
#pragma unroll
        for (int i = 0; i < 4; i++)
            af[i] = *(const bf16x8*)&As[b][(waveM + i * 16 + l16) * 32 + quad * 8];
#pragma unroll
        for (int j = 0; j < 4; j++)
            bfv[j] = *(const bf16x8*)&Bs[b][(waveN + j * 16 + l16) * 32 + quad * 8];
#pragma unroll
        for (int i = 0; i < 4; i++)
#pragma unroll
            for (int j = 0; j < 4; j++)
                acc[i][j] = mfma16(af[i], bfv[j], acc[i][j]);
        __syncthreads();  // drains prefetch (issued ~compute-phase ago) + sync
    }
    // C/D layout: col = lane&15, row = quad*4 + reg (verified m89/m91)
#pragma unroll
    for (int i = 0; i < 4; i++)
#pragma unroll
        for (int j = 0; j < 4; j++)
#pragma unroll
            for (int r = 0; r < 4; r++) {
                int row = m0 + waveM + i * 16 + quad * 4 + r;
                int col = n0 + waveN + j * 16 + l16;
                if constexpr (sizeof(OutT) == 2)
                    C[(size_t)row * N + col] = f2bf(acc[i][j][r]);
                else
                    C[(size_t)row * N + col] = acc[i][j][r];
            }
}

// ---------------------------------------------------------------------------
// RoPE in-place on bf16 X[S][...], row stride `stride` elements; head count
// 2^log2nh at cols h*128. cos/sin fp32 [S][128].
// ---------------------------------------------------------------------------
__global__ __launch_bounds__(256) void rope_kernel(
    unsigned short* __restrict__ X, const float* __restrict__ cb,
    const float* __restrict__ sb, int log2nh, int stride) {
    int idx = blockIdx.x * 256 + threadIdx.x;
    int d = idx & 63;
    int h = (idx >> 6) & ((1 << log2nh) - 1);
    int s = idx >> (6 + log2nh);
    size_t base = (size_t)s * stride + h * HD + d;
    float a = bf2f(X[base]);
    float b = bf2f(X[base + 64]);
    float c0 = cb[s * HD + d];
    float s0 = sb[s * HD + d];
    float c1 = cb[s * HD + d + 64];
    float s1 = sb[s * HD + d + 64];
    X[base]      = f2bf(a * c0 - b * s0);
    X[base + 64] = f2bf(b * c1 + a * s1);
}

// ---------------------------------------------------------------------------
// Flash attention, causal, GQA 16Q/4KV, hd=128.
// LDS-BANDWIDTH structure at 2-blocks/CU occupancy: q-block = 128 rows,
// each wave owns 32 q-rows (2 x 16-row tiles), k-chunk = 32. Each wave
// reads the K tile (8 KB) and V tile (8 KB) ONCE per chunk, used for BOTH
// q-tiles -> ~23 B LDS traffic per k*q unit (vs ~37 B for 1-q-tile/wave).
// LDS = 16K (K dbuf) + 16K (V dbuf) + 4K (Ps) = 36 KB. Measured pool:
// 2x36=72 KB fits (R2: 2 blocks/CU), 2x40=80 does NOT (R5: 1 block/CU) ->
// Ps halved to 4 KB by TIME-SHARING one 2-slot per-wave buffer across the
// two q-tiles (write P(i) -> read pf[i] -> overwrite with P(i+1); DS pipe
// is in-order within a wave, wave-private data, no barrier needed).
// __launch_bounds__(256, 2): (256,4)+ caps VGPR at 64 and spilled (R4).
// Double-buffered global_load_lds staging, one __syncthreads per chunk,
// prefetch issued a full compute-phase before the drain. Balanced per-CU
// pairing: blocks i and i+256 share a CU, qb sums = 31.
// ---------------------------------------------------------------------------
__global__ __launch_bounds__(256, 2) void attn_kernel(
    const unsigned short* __restrict__ Q, const unsigned short* __restrict__ Kv,
    const unsigned short* __restrict__ Vt, unsigned short* __restrict__ O) {
    __shared__ __align__(16) unsigned short Kt[2][32 * 128];   // 8 KB per buf
    __shared__ __align__(16) unsigned short Vs[2][128 * 32];   // 8 KB per buf
    __shared__ __align__(16) unsigned long long Ps[4 * 2 * 64]; // 4 KB
    const int tid = threadIdx.x;
    const int wave = tid >> 6, lane = tid & 63, quad = lane >> 4, l16 = lane & 15;
    const int id = blockIdx.x;
    const int h = id & 15;
    const int qb = (id < 256) ? (31 - (id >> 4)) : ((id - 256) >> 4);
    const int kvh = h >> 2;
    const int rowbase = qb * 128 + wave * 32;
    unsigned long long* Pw = &Ps[wave * 2 * 64];
    const float cexp = 0.08838834764831845f * 1.44269504088896f;  // scale*log2(e)

    // stage chunk c (32 k-rows): K 8KB + V 8KB, 2 segs/wave each.
    auto stage = [&](int c, int b) {
        const int kb = c * 32;
#pragma unroll
        for (int u = 0; u < 2; u++) {
            const int seg = wave * 2 + u;
            const int idx = seg * 64 + lane;
            {   // K tile [32 k][128 d], 16 granules/row, swizzle cs ^ (r&15)
                const int r = idx >> 4, cs = idx & 15, cl = cs ^ (r & 15);
                async16(&Kt[b][seg * 512],
                        &Kv[(size_t)(kb + r) * QKV_N + kvh * HD + cl * 8]);
            }
            {   // V tile [128 d][32 k], 4 granules/row, swizzle cs ^ ((r>>1)&3)
                const int r = idx >> 2, cs = idx & 3, cl = cs ^ ((r >> 1) & 3);
                async16(&Vs[b][seg * 512],
                        &Vt[(size_t)(kvh * HD + r) * S_LEN + kb + cl * 8]);
            }
        }
    };

    // Q fragments (2 q-tiles x 16 rows per wave, reused across all chunks).
    bf16x8 qf[2][4];
#pragma unroll
    for (int i = 0; i < 2; i++)
#pragma unroll
        for (int dd = 0; dd < 4; dd++)
            qf[i][dd] = *(const bf16x8*)&Q[(size_t)(rowbase + i * 16 + l16) * QKV_N +
                                           h * HD + dd * 32 + quad * 8];

    f32x4 oacc[2][8] = {};
    float lrow[2] = {0.0f, 0.0f};
    const int qa0 = rowbase + l16;
    const int qa1 = rowbase + 16 + l16;
    const int nch = 4 * qb + 4;

    stage(0, 0);
    __syncthreads();
    for (int c = 0; c < nch; c++) {
        const int b = c & 1;
        if (c + 1 < nch) stage(c + 1, b ^ 1);
        const int kb = c * 32;
        if (kb <= rowbase + 31) {  // per-wave skip of fully-masked chunks
            const bool diag = (kb + 31 > rowbase);
            // ---- S^T tiles jl = 0,1 (m = k-pos, n = q), both q-tiles ----
            f32x4 sacc[2][2] = {};
            __builtin_amdgcn_s_setprio(1);
#pragma unroll
            for (int dd = 0; dd < 4; dd++) {
                const int csw = (dd * 4 + quad) ^ l16;
                bf16x8 kf0 = *(const bf16x8*)&Kt[b][((0 * 16 + l16) * 16 + csw) * 8];
                bf16x8 kf1 = *(const bf16x8*)&Kt[b][((1 * 16 + l16) * 16 + csw) * 8];
                sacc[0][0] = mfma16(kf0, qf[0][dd], sacc[0][0]);
                sacc[0][1] = mfma16(kf1, qf[0][dd], sacc[0][1]);
                sacc[1][0] = mfma16(kf0, qf[1][dd], sacc[1][0]);
                sacc[1][1] = mfma16(kf1, qf[1][dd], sacc[1][1]);
            }
            __builtin_amdgcn_s_setprio(0);
            // ---- per q-tile: exp, mask, pack -> 2-slot LDS, read back pf ----
            bf16x8 pf[2];
#pragma unroll
            for (int i = 0; i < 2; i++) {
                const int qa = i ? qa1 : qa0;
#pragma unroll
                for (int jl = 0; jl < 2; jl++) {
                    const int kg = kb + 16 * jl + 4 * quad;
                    float p0 = fast_exp2(sacc[i][jl][0] * cexp);
                    float p1 = fast_exp2(sacc[i][jl][1] * cexp);
                    float p2 = fast_exp2(sacc[i][jl][2] * cexp);
                    float p3 = fast_exp2(sacc[i][jl][3] * cexp);
                    if (diag) {
                        if (kg + 0 > qa) p0 = 0.0f;
                        if (kg + 1 > qa) p1 = 0.0f;
                        if (kg + 2 > qa) p2 = 0.0f;
                        if (kg + 3 > qa) p3 = 0.0f;
                    }
                    lrow[i] += (p0 + p1) + (p2 + p3);
                    unsigned int lo = cvt_pk_bf16(p0, p1);
                    unsigned int hi = cvt_pk_bf16(p2, p3);
                    Pw[jl * 64 + lane] =
                        (unsigned long long)lo | ((unsigned long long)hi << 32);
                }
                // read back this q-tile's A-fragment (wave-private, DS pipe
                // is in-order within a wave -> no barrier; the i=1 writes
                // cannot pass the i=0 reads)
                const unsigned long long* src =
                    &Pw[(quad >> 1) * 64 + l16 + 32 * (quad & 1)];
                u64x2 t;
                t[0] = src[0];
                t[1] = src[16];
                pf[i] = __builtin_bit_cast(bf16x8, t);
            }
            // ---- O += P V: V tile read ONCE, used for both q-tiles ----
            const int vsw0 = (quad ^ ((l16 >> 1) & 3)) * 8;
            __builtin_amdgcn_s_setprio(1);
#pragma unroll
            for (int jd = 0; jd < 8; jd++) {
                bf16x8 vf = *(const bf16x8*)&Vs[b][(jd * 16 + l16) * 32 + vsw0];
                oacc[0][jd] = mfma16(pf[0], vf, oacc[0][jd]);
                oacc[1][jd] = mfma16(pf[1], vf, oacc[1][jd]);
            }
            __builtin_amdgcn_s_setprio(0);
        }
        __syncthreads();  // drains prefetch (issued compute-phase ago) + sync
    }
    // ---- epilogue: row sums, O /= l, write [S][NH*HD] ----
    float lsum[2];
#pragma unroll
    for (int i = 0; i < 2; i++) {
        float l = lrow[i];
        l += __shfl_xor(l, 16, 64);
        l += __shfl_xor(l, 32, 64);
        lsum[i] = l;
    }
#pragma unroll
    for (int i = 0; i < 2; i++)
#pragma unroll
        for (int r = 0; r < 4; r++) {
            float lq = __shfl(lsum[i], quad * 4 + r, 64);
            float inv = 1.0f / lq;
            int row = rowbase + i * 16 + quad * 4 + r;
#pragma unroll
            for (int jd = 0; jd < 8; jd++)
                O[(size_t)row * DMODEL + h * HD + jd * 16 + l16] = f2bf(oacc[i][jd][r] * inv);
        }
}

// ---------------------------------------------------------------------------
extern "C" void kernel_launch(void* const* d_in, const int* in_sizes, int n_in,
                              void* d_out, int out_size, void* d_ws, size_t ws_size,
                              hipStream_t stream) {
    const float* X  = (const float*)d_in[0];  // hidden [4096][2048]
    const float* cb = (const float*)d_in[1];  // cos [4096][128]
    const float* sb = (const float*)d_in[2];  // sin [4096][128]
    const float* Wq = (const float*)d_in[3];  // [2048][2048]
    const float* Wk = (const float*)d_in[4];  // [2048][512]
    const float* Wv = (const float*)d_in[5];  // [2048][512]
    const float* Wo = (const float*)d_in[6];  // [2048][2048]
    float* out = (float*)d_out;               // [4096][2048] fp32

    char* ws = (char*)d_ws;
    size_t off = 0;
    auto alloc = [&](size_t bytes) { char* p = ws + off; off += (bytes + 255) & ~(size_t)255; return p; };
    unsigned short* Xb    = (unsigned short*)alloc((size_t)S_LEN * DMODEL * 2);
    unsigned short* QKVb  = (unsigned short*)alloc((size_t)S_LEN * QKV_N * 2);   // [4096][3072]
    unsigned short* Vtb   = (unsigned short*)alloc((size_t)S_LEN * NKV * HD * 2); // [512][4096]
    unsigned short* Ob    = (unsigned short*)alloc((size_t)S_LEN * DMODEL * 2);
    unsigned short* WqkvT = (unsigned short*)alloc((size_t)QKV_N * DMODEL * 2);  // [3072][2048]
    unsigned short* WoT   = (unsigned short*)alloc((size_t)DMODEL * DMODEL * 2);

    // hidden fp32 -> bf16
    conv_f32_bf16<<<(S_LEN * DMODEL / 4 + 255) / 256, 256, 0, stream>>>(X, Xb, S_LEN * DMODEL / 4);

    dim3 tb(32, 32);
    // Weight transposes (fp32 -> bf16), stacked [Wq^T; Wk^T; Wv^T] = [3072][2048].
    transpose_f32_bf16<<<dim3(DMODEL / 32, DMODEL / 32), tb, 0, stream>>>(Wq, WqkvT, DMODEL, DMODEL);
    transpose_f32_bf16<<<dim3((NKV * HD) / 32, DMODEL / 32), tb, 0, stream>>>(Wk, WqkvT + (size_t)DMODEL * DMODEL, DMODEL, NKV * HD);
    transpose_f32_bf16<<<dim3((NKV * HD) / 32, DMODEL / 32), tb, 0, stream>>>(Wv, WqkvT + (size_t)(DMODEL + NKV * HD) * DMODEL, DMODEL, NKV * HD);
    transpose_f32_bf16<<<dim3(DMODEL / 32, DMODEL / 32), tb, 0, stream>>>(Wo, WoT, DMODEL, DMODEL);

    // Merged QKV projection: N = 3072 (cols 0..2047 Q | 2048..2559 K | 2560..3071 V)
    gemm_bt<unsigned short><<<dim3(S_LEN / 128, QKV_N / 128), 256, 0, stream>>>(Xb, WqkvT, QKVb, QKV_N, DMODEL);

    // RoPE in place: Q (stride 3072, 16 heads), K (stride 3072, 4 heads)
    rope_kernel<<<(S_LEN * NH * 64) / 256, 256, 0, stream>>>(QKVb, cb, sb, 4, QKV_N);
    rope_kernel<<<(S_LEN * NKV * 64) / 256, 256, 0, stream>>>(QKVb + DMODEL, cb, sb, 2, QKV_N);

    // V columns of QKVb -> Vt [512][4096]
    transpose_bf16<<<dim3((NKV * HD) / 32, S_LEN / 32), tb, 0, stream>>>(
        QKVb + DMODEL + NKV * HD, Vtb, S_LEN, NKV * HD, QKV_N);

    // Flash attention: 512 blocks (q-block=128), 36 KB LDS -> 2 blocks/CU
    attn_kernel<<<512, 256, 0, stream>>>(QKVb, QKVb + DMODEL, Vtb, Ob);

    // Output projection (fp32 out)
    gemm_bt<float><<<dim3(S_LEN / 128, DMODEL / 128), 256, 0, stream>>>(Ob, WoT, out, DMODEL, DMODEL);
}

// Round 8
// 379.123 us; speedup vs baseline: 1.5698x; 1.0830x over previous
//
#include <hip/hip_runtime.h>
#include <hip/hip_bf16.h>

// Problem constants
#define S_LEN 4096
#define DMODEL 2048
#define NH 16
#define NKV 4
#define HD 128
#define QKV_N 3072   // merged QKV projection width: 2048 Q | 512 K | 512 V

typedef __bf16 bf16x8 __attribute__((ext_vector_type(8)));
typedef float f32x4 __attribute__((ext_vector_type(4)));
typedef unsigned short u16x8 __attribute__((ext_vector_type(8)));
typedef unsigned short u16x4 __attribute__((ext_vector_type(4)));
typedef unsigned long long u64x2 __attribute__((ext_vector_type(2)));

__device__ __forceinline__ unsigned short f2bf(float f) {
    unsigned int u = __builtin_bit_cast(unsigned int, f);
    u += 0x7fffu + ((u >> 16) & 1u);   // round-to-nearest-even
    return (unsigned short)(u >> 16);
}
__device__ __forceinline__ float bf2f(unsigned short h) {
    unsigned int u = ((unsigned int)h) << 16;
    return __builtin_bit_cast(float, u);
}

// Single-instruction packed f32x2 -> bf16x2 (RTNE).
__device__ __forceinline__ unsigned int cvt_pk_bf16(float lo, float hi) {
    unsigned int r;
    asm("v_cvt_pk_bf16_f32 %0, %1, %2" : "=v"(r) : "v"(lo), "v"(hi));
    return r;
}

// Raw v_exp_f32 (2^x); skips ocml denorm fixup.
__device__ __forceinline__ float fast_exp2(float x) {
    float r;
    asm("v_exp_f32 %0, %1" : "=v"(r) : "v"(x));
    return r;
}

__device__ __forceinline__ f32x4 mfma16(bf16x8 a, bf16x8 b, f32x4 c) {
    return __builtin_amdgcn_mfma_f32_16x16x32_bf16(a, b, c, 0, 0, 0);
}

// Async global->LDS DMA, 16B per lane. LDS dest = wave-uniform base + lane*16.
__device__ __forceinline__ void async16(unsigned short* lds, const unsigned short* g) {
    __builtin_amdgcn_global_load_lds((__attribute__((address_space(1))) void*)g,
                                     (__attribute__((address_space(3))) void*)lds,
                                     16, 0, 0);
}

// ---------------------------------------------------------------------------
// fp32 -> bf16 elementwise convert (4 elems/thread, float4 loads)
// ---------------------------------------------------------------------------
__global__ __launch_bounds__(256) void conv_f32_bf16(
    const float* __restrict__ in, unsigned short* __restrict__ out, int n4) {
    int i = blockIdx.x * 256 + threadIdx.x;
    if (i >= n4) return;
    float4 v = *(const float4*)&in[(size_t)i * 4];
    u16x4 o;
    o[0] = f2bf(v.x); o[1] = f2bf(v.y); o[2] = f2bf(v.z); o[3] = f2bf(v.w);
    *(u16x4*)&out[(size_t)i * 4] = o;
}

// ---------------------------------------------------------------------------
// Tiled transpose fp32 in[R][C] -> bf16 out[C][R]. R, C multiples of 32.
// ---------------------------------------------------------------------------
__global__ __launch_bounds__(1024) void transpose_f32_bf16(
    const float* __restrict__ in, unsigned short* __restrict__ out,
    int R, int C) {
    __shared__ float tile[32][33];
    int x = blockIdx.x * 32 + threadIdx.x;
    int y = blockIdx.y * 32 + threadIdx.y;
    tile[threadIdx.y][threadIdx.x] = in[(size_t)y * C + x];
    __syncthreads();
    int ox = blockIdx.y * 32 + threadIdx.x;
    int oy = blockIdx.x * 32 + threadIdx.y;
    out[(size_t)oy * R + ox] = f2bf(tile[threadIdx.x][threadIdx.y]);
}

// ---------------------------------------------------------------------------
// Tiled bf16 transpose with input row stride: in[y*ldin + x] (y<R rows, x<C
// cols) -> out[C][R] contiguous.
// ---------------------------------------------------------------------------
__global__ __launch_bounds__(1024) void transpose_bf16(
    const unsigned short* __restrict__ in, unsigned short* __restrict__ out,
    int R, int C, int ldin) {
    __shared__ unsigned short tile[32][33];
    int x = blockIdx.x * 32 + threadIdx.x;
    int y = blockIdx.y * 32 + threadIdx.y;
    tile[threadIdx.y][threadIdx.x] = in[(size_t)y * ldin + x];
    __syncthreads();
    int ox = blockIdx.y * 32 + threadIdx.x;
    int oy = blockIdx.x * 32 + threadIdx.y;
    out[(size_t)oy * R + ox] = tile[threadIdx.x][threadIdx.y];
}

// ---------------------------------------------------------------------------
// C[M,N] = A[M,K] * B[K,N], B given transposed (Bt[N][K]). bf16 in, fp32
// accumulate, OutT out. 128x128 tile, BK=32, 4 waves of 64x64.
// ---------------------------------------------------------------------------
template <typename OutT>
__global__ __launch_bounds__(256) void gemm_bt(
    const unsigned short* __restrict__ A, const unsigned short* __restrict__ Bt,
    OutT* __restrict__ C, int N, int K) {
    __shared__ __align__(16) unsigned short As[2][128 * 32];  // 8 KB per buf
    __shared__ __align__(16) unsigned short Bs[2][128 * 32];
    const int tid = threadIdx.x;
    const int wave = tid >> 6, lane = tid & 63, quad = lane >> 4, l16 = lane & 15;
    const int m0 = blockIdx.x * 128, n0 = blockIdx.y * 128;
    const int waveM = (wave & 1) * 64, waveN = (wave >> 1) * 64;
    f32x4 acc[4][4] = {};

    auto stage = [&](int k0, int b) {
#pragma unroll
        for (int u = 0; u < 2; u++) {
            const int seg = wave * 2 + u;
            const int idx = seg * 64 + lane;
            const int r = idx >> 2, c = idx & 3;  // granule (r, c): 4x16B per row
            async16(&As[b][seg * 512], &A[(size_t)(m0 + r) * K + k0 + c * 8]);
            async16(&Bs[b][seg * 512], &Bt[(size_t)(n0 + r) * K + k0 + c * 8]);
        }
    };

    const int niter = K / 32;
    stage(0, 0);
    __syncthreads();  // drains vmcnt -> buf0 ready
    for (int it = 0; it < niter; it++) {
        const int b = it & 1;
        if (it + 1 < niter) stage((it + 1) * 32, b ^ 1);
        bf16x8 af[4], bfv[4];
#pragma unroll
        for (int i = 0; i < 4; i++)
            af[i] = *(const bf16x8*)&As[b][(waveM + i * 16 + l16) * 32 + quad * 8];
#pragma unroll
        for (int j = 0; j < 4; j++)
            bfv[j] = *(const bf16x8*)&Bs[b][(waveN + j * 16 + l16) * 32 + quad * 8];
#pragma unroll
        for (int i = 0; i < 4; i++)
#pragma unroll
            for (int j = 0; j < 4; j++)
                acc[i][j] = mfma16(af[i], bfv[j], acc[i][j]);
        __syncthreads();  // drains prefetch (issued ~compute-phase ago) + sync
    }
    // C/D layout: col = lane&15, row = quad*4 + reg (verified m89/m91)
#pragma unroll
    for (int i = 0; i < 4; i++)
#pragma unroll
        for (int j = 0; j < 4; j++)
#pragma unroll
            for (int r = 0; r < 4; r++) {
                int row = m0 + waveM + i * 16 + quad * 4 + r;
                int col = n0 + waveN + j * 16 + l16;
                if constexpr (sizeof(OutT) == 2)
                    C[(size_t)row * N + col] = f2bf(acc[i][j][r]);
                else
                    C[(size_t)row * N + col] = acc[i][j][r];
            }
}

// ---------------------------------------------------------------------------
// RoPE in-place on bf16 X[S][...], row stride `stride` elements; head count
// 2^log2nh at cols h*128. cos/sin fp32 [S][128]. Vectorized: each thread
// handles 4 consecutive d (u16x4 + float4 loads) -- G13.
// ---------------------------------------------------------------------------
__global__ __launch_bounds__(256) void rope_kernel(
    unsigned short* __restrict__ X, const float* __restrict__ cb,
    const float* __restrict__ sb, int log2nh, int stride) {
    int idx = blockIdx.x * 256 + threadIdx.x;
    int d4 = idx & 15;                       // 16 groups of 4 halves
    int h = (idx >> 4) & ((1 << log2nh) - 1);
    int s = idx >> (4 + log2nh);
    size_t base = (size_t)s * stride + h * HD + d4 * 4;
    u16x4 a = *(const u16x4*)&X[base];
    u16x4 b = *(const u16x4*)&X[base + 64];
    float4 c0 = *(const float4*)&cb[s * HD + d4 * 4];
    float4 s0 = *(const float4*)&sb[s * HD + d4 * 4];
    float4 c1 = *(const float4*)&cb[s * HD + 64 + d4 * 4];
    float4 s1 = *(const float4*)&sb[s * HD + 64 + d4 * 4];
    u16x4 oa, ob;
#pragma unroll
    for (int e = 0; e < 4; e++) {
        float af = bf2f(a[e]), bf = bf2f(b[e]);
        float ce0 = (e == 0) ? c0.x : (e == 1) ? c0.y : (e == 2) ? c0.z : c0.w;
        float se0 = (e == 0) ? s0.x : (e == 1) ? s0.y : (e == 2) ? s0.z : s0.w;
        float ce1 = (e == 0) ? c1.x : (e == 1) ? c1.y : (e == 2) ? c1.z : c1.w;
        float se1 = (e == 0) ? s1.x : (e == 1) ? s1.y : (e == 2) ? s1.z : s1.w;
        oa[e] = f2bf(af * ce0 - bf * se0);
        ob[e] = f2bf(bf * ce1 + af * se1);
    }
    *(u16x4*)&X[base] = oa;
    *(u16x4*)&X[base + 64] = ob;
}

// ---------------------------------------------------------------------------
// Flash attention, causal, GQA 16Q/4KV, hd=128. PROVEN R2 STRUCTURE (134 us,
// occupancy 24.6%, VGPR 52, passed): q-block = 64 rows (1 wave = 16 q-rows),
// k-chunk = 32, LDS 36 KB (K dbuf 16K + V dbuf 16K + Ps 4K) -> 2 blocks/CU
// sustained via backfill (grid 1024 > 512 resident slots). Double-buffered
// global_load_lds staging, one __syncthreads per chunk, prefetch issued a
// full compute-phase before the drain. P via wave-private LDS round-trip,
// write-once-read-once per chunk (no time-sharing). Balanced quartet map.
// ---------------------------------------------------------------------------
__global__ __launch_bounds__(256, 4) void attn_kernel(
    const unsigned short* __restrict__ Q, const unsigned short* __restrict__ Kv,
    const unsigned short* __restrict__ Vt, unsigned short* __restrict__ O) {
    __shared__ __align__(16) unsigned short Kt[2][32 * 128];   // 8 KB per buf
    __shared__ __align__(16) unsigned short Vs[2][128 * 32];   // 8 KB per buf
    __shared__ __align__(16) unsigned long long Ps[4 * 2 * 64]; // 4 KB
    const int tid = threadIdx.x;
    const int wave = tid >> 6, lane = tid & 63, quad = lane >> 4, l16 = lane & 15;
    const int id = blockIdx.x;
    const int h = id & 15;
    const int grp = id >> 4, g = grp & 15, quarter = grp >> 4;
    const int qb = quarter == 0 ? 63 - g : quarter == 1 ? g
                 : quarter == 2 ? 32 + g : 31 - g;
    const int kvh = h >> 2;
    const int rowbase = qb * 64 + wave * 16;
    unsigned long long* Pw = &Ps[wave * 2 * 64];
    const float cexp = 0.08838834764831845f * 1.44269504088896f;  // scale*log2(e)

    // stage chunk c (32 k-rows): K 8KB + V 8KB, 2 segs/wave each.
    auto stage = [&](int c, int b) {
        const int kb = c * 32;
#pragma unroll
        for (int u = 0; u < 2; u++) {
            const int seg = wave * 2 + u;
            const int idx = seg * 64 + lane;
            {   // K tile [32 k][128 d], 16 granules/row, swizzle cs ^ (r&15)
                const int r = idx >> 4, cs = idx & 15, cl = cs ^ (r & 15);
                async16(&Kt[b][seg * 512],
                        &Kv[(size_t)(kb + r) * QKV_N + kvh * HD + cl * 8]);
            }
            {   // V tile [128 d][32 k], 4 granules/row, swizzle cs ^ ((r>>1)&3)
                const int r = idx >> 2, cs = idx & 3, cl = cs ^ ((r >> 1) & 3);
                async16(&Vs[b][seg * 512],
                        &Vt[(size_t)(kvh * HD + r) * S_LEN + kb + cl * 8]);
            }
        }
    };

    // Q fragments (16 q-rows per wave, reused across all chunks).
    bf16x8 qf[4];
#pragma unroll
    for (int dd = 0; dd < 4; dd++)
        qf[dd] = *(const bf16x8*)&Q[(size_t)(rowbase + l16) * QKV_N +
                                     h * HD + dd * 32 + quad * 8];

    f32x4 oacc[8] = {};
    float lrow = 0.0f;
    const int qa = rowbase + l16;
    const int nch = 2 * qb + 2;

    stage(0, 0);
    __syncthreads();
    for (int c = 0; c < nch; c++) {
        const int b = c & 1;
        if (c + 1 < nch) stage(c + 1, b ^ 1);
        const int kb = c * 32;
        if (kb <= rowbase + 15) {  // per-wave skip of fully-masked chunks
            const bool diag = (kb + 31 > rowbase);
            // ---- S^T tiles tj = 0,1 (m = k-pos, n = q) ----
            f32x4 sacc[2] = {};
            __builtin_amdgcn_s_setprio(1);
#pragma unroll
            for (int dd = 0; dd < 4; dd++) {
                const int csw = (dd * 4 + quad) ^ l16;
                bf16x8 kf0 = *(const bf16x8*)&Kt[b][((0 * 16 + l16) * 16 + csw) * 8];
                bf16x8 kf1 = *(const bf16x8*)&Kt[b][((1 * 16 + l16) * 16 + csw) * 8];
                sacc[0] = mfma16(kf0, qf[dd], sacc[0]);
                sacc[1] = mfma16(kf1, qf[dd], sacc[1]);
            }
            __builtin_amdgcn_s_setprio(0);
            // ---- exp, mask, l-partials, pack 4 bf16 -> one 8B LDS write ----
#pragma unroll
            for (int jl = 0; jl < 2; jl++) {
                const int kg = kb + 16 * jl + 4 * quad;
                float p0 = fast_exp2(sacc[jl][0] * cexp);
                float p1 = fast_exp2(sacc[jl][1] * cexp);
                float p2 = fast_exp2(sacc[jl][2] * cexp);
                float p3 = fast_exp2(sacc[jl][3] * cexp);
                if (diag) {
                    if (kg + 0 > qa) p0 = 0.0f;
                    if (kg + 1 > qa) p1 = 0.0f;
                    if (kg + 2 > qa) p2 = 0.0f;
                    if (kg + 3 > qa) p3 = 0.0f;
                }
                lrow += (p0 + p1) + (p2 + p3);
                unsigned int lo = cvt_pk_bf16(p0, p1);
                unsigned int hi = cvt_pk_bf16(p2, p3);
                Pw[jl * 64 + lane] =
                    (unsigned long long)lo | ((unsigned long long)hi << 32);
            }
            // ---- P A-fragment: two 8B wave-private LDS reads ----
            bf16x8 pf;
            {
                const unsigned long long* src =
                    &Pw[(quad >> 1) * 64 + l16 + 32 * (quad & 1)];
                u64x2 t;
                t[0] = src[0];
                t[1] = src[16];
                pf = __builtin_bit_cast(bf16x8, t);
            }
            // ---- O += P V for this 32-k chunk ----
            const int vsw0 = (quad ^ ((l16 >> 1) & 3)) * 8;
            __builtin_amdgcn_s_setprio(1);
#pragma unroll
            for (int jd = 0; jd < 8; jd++) {
                bf16x8 vf = *(const bf16x8*)&Vs[b][(jd * 16 + l16) * 32 + vsw0];
                oacc[jd] = mfma16(pf, vf, oacc[jd]);
            }
            __builtin_amdgcn_s_setprio(0);
        }
        __syncthreads();  // drains prefetch + sync
    }
    // ---- epilogue: row sums, O /= l, write [S][NH*HD] ----
    float lsum;
    {
        float l = lrow;
        l += __shfl_xor(l, 16, 64);
        l += __shfl_xor(l, 32, 64);
        lsum = l;  // every lane: sum for q-row rowbase + l16
    }
#pragma unroll
    for (int r = 0; r < 4; r++) {
        float lq = __shfl(lsum, quad * 4 + r, 64);
        float inv = 1.0f / lq;
        int row = rowbase + quad * 4 + r;
#pragma unroll
        for (int jd = 0; jd < 8; jd++)
            O[(size_t)row * DMODEL + h * HD + jd * 16 + l16] = f2bf(oacc[jd][r] * inv);
    }
}

// ---------------------------------------------------------------------------
extern "C" void kernel_launch(void* const* d_in, const int* in_sizes, int n_in,
                              void* d_out, int out_size, void* d_ws, size_t ws_size,
                              hipStream_t stream) {
    const float* X  = (const float*)d_in[0];  // hidden [4096][2048]
    const float* cb = (const float*)d_in[1];  // cos [4096][128]
    const float* sb = (const float*)d_in[2];  // sin [4096][128]
    const float* Wq = (const float*)d_in[3];  // [2048][2048]
    const float* Wk = (const float*)d_in[4];  // [2048][512]
    const float* Wv = (const float*)d_in[5];  // [2048][512]
    const float* Wo = (const float*)d_in[6];  // [2048][2048]
    float* out = (float*)d_out;               // [4096][2048] fp32

    char* ws = (char*)d_ws;
    size_t off = 0;
    auto alloc = [&](size_t bytes) { char* p = ws + off; off += (bytes + 255) & ~(size_t)255; return p; };
    unsigned short* Xb    = (unsigned short*)alloc((size_t)S_LEN * DMODEL * 2);
    unsigned short* QKVb  = (unsigned short*)alloc((size_t)S_LEN * QKV_N * 2);   // [4096][3072]
    unsigned short* Vtb   = (unsigned short*)alloc((size_t)S_LEN * NKV * HD * 2); // [512][4096]
    unsigned short* Ob    = (unsigned short*)alloc((size_t)S_LEN * DMODEL * 2);
    unsigned short* WqkvT = (unsigned short*)alloc((size_t)QKV_N * DMODEL * 2);  // [3072][2048]
    unsigned short* WoT   = (unsigned short*)alloc((size_t)DMODEL * DMODEL * 2);

    // hidden fp32 -> bf16
    conv_f32_bf16<<<(S_LEN * DMODEL / 4 + 255) / 256, 256, 0, stream>>>(X, Xb, S_LEN * DMODEL / 4);

    dim3 tb(32, 32);
    // Weight transposes (fp32 -> bf16), stacked [Wq^T; Wk^T; Wv^T] = [3072][2048].
    transpose_f32_bf16<<<dim3(DMODEL / 32, DMODEL / 32), tb, 0, stream>>>(Wq, WqkvT, DMODEL, DMODEL);
    transpose_f32_bf16<<<dim3((NKV * HD) / 32, DMODEL / 32), tb, 0, stream>>>(Wk, WqkvT + (size_t)DMODEL * DMODEL, DMODEL, NKV * HD);
    transpose_f32_bf16<<<dim3((NKV * HD) / 32, DMODEL / 32), tb, 0, stream>>>(Wv, WqkvT + (size_t)(DMODEL + NKV * HD) * DMODEL, DMODEL, NKV * HD);
    transpose_f32_bf16<<<dim3(DMODEL / 32, DMODEL / 32), tb, 0, stream>>>(Wo, WoT, DMODEL, DMODEL);

    // Merged QKV projection: N = 3072 (cols 0..2047 Q | 2048..2559 K | 2560..3071 V)
    gemm_bt<unsigned short><<<dim3(S_LEN / 128, QKV_N / 128), 256, 0, stream>>>(Xb, WqkvT, QKVb, QKV_N, DMODEL);

    // RoPE in place (vectorized x4): Q (16 heads), K (4 heads), stride 3072
    rope_kernel<<<(S_LEN * NH * 16) / 256, 256, 0, stream>>>(QKVb, cb, sb, 4, QKV_N);
    rope_kernel<<<(S_LEN * NKV * 16) / 256, 256, 0, stream>>>(QKVb + DMODEL, cb, sb, 2, QKV_N);

    // V columns of QKVb -> Vt [512][4096]
    transpose_bf16<<<dim3((NKV * HD) / 32, S_LEN / 32), tb, 0, stream>>>(
        QKVb + DMODEL + NKV * HD, Vtb, S_LEN, NKV * HD, QKV_N);

    // Flash attention: 1024 blocks (q-block=64), 36 KB LDS -> 2 blocks/CU
    attn_kernel<<<1024, 256, 0, stream>>>(QKVb, QKVb + DMODEL, Vtb, Ob);

    // Output projection (fp32 out)
    gemm_bt<float><<<dim3(S_LEN / 128, DMODEL / 128), 256, 0, stream>>>(Ob, WoT, out, DMODEL, DMODEL);
}